// Round 4
// baseline (105.381 us; speedup 1.0000x reference)
//
#include <hip/hip_runtime.h>
#include <math.h>

#define ALPHA 0.2f

constexpr int B = 32, N = 1024, C = 64;

typedef __attribute__((ext_vector_type(8))) short short8;
typedef __attribute__((ext_vector_type(4))) float floatx4;

static __device__ __forceinline__ unsigned f32bf(float f) {
    unsigned u = __float_as_uint(f);
    return (u + 0x7FFFu + ((u >> 16) & 1u)) >> 16;   // RNE; no NaNs here
}

// ---------------- Kernel M: adj -> bitmask; also wa = W @ a_src/a_dst -----
__global__ __launch_bounds__(256) void gat_mask(const float* __restrict__ adj,
                                                const float* __restrict__ Wm,
                                                const float* __restrict__ a,
                                                unsigned long long* __restrict__ mask64,
                                                float* __restrict__ wa)
{
    const int lane = threadIdx.x & 63;
    const int wave = threadIdx.x >> 6;
    const int id   = blockIdx.x * 4 + wave;      // 0..16383
    const int i    = id >> 4;
    const int jc   = id & 15;
    const float av = adj[(size_t)i * N + jc * 64 + lane];
    const unsigned long long bal = __ballot(av > 0.5f);
    if (lane == 0) mask64[i * 16 + jc] = bal;

    if (blockIdx.x == 0 && wave == 0) {          // wa[k] = sum_c W[k][c]*a[c]
        float accs = 0.f, accd = 0.f;
#pragma unroll
        for (int c4 = 0; c4 < 16; ++c4) {
            const float4 wv = *(const float4*)&Wm[lane * 64 + c4 * 4];
            const float4 as = *(const float4*)&a[c4 * 4];
            const float4 ad = *(const float4*)&a[64 + c4 * 4];
            accs = fmaf(wv.x, as.x, fmaf(wv.y, as.y, fmaf(wv.z, as.z, fmaf(wv.w, as.w, accs))));
            accd = fmaf(wv.x, ad.x, fmaf(wv.y, ad.y, fmaf(wv.z, ad.z, fmaf(wv.w, ad.w, accd))));
        }
        wa[lane] = accs;
        wa[64 + lane] = accd;
    }
}

// ---------------- Kernel A: hT(bf16) = (input@W)^T per batch; s vectors ----
__global__ __launch_bounds__(256) void gat_hs(const float* __restrict__ input,
                                              const float* __restrict__ Wm,
                                              const float* __restrict__ wa,
                                              unsigned short* __restrict__ hT,
                                              float* __restrict__ ssrc,
                                              float* __restrict__ sdst)
{
    __shared__ __align__(16) float ins[64 * 68];          // padded rows
    __shared__ __align__(16) unsigned short hsT[64 * 72]; // [c][row] padded
    __shared__ float red_s[256], red_d[256];
    __shared__ float wa_l[128];

    const int tid  = threadIdx.x;
    const int lane = tid & 63;
    const int wave = tid >> 6;
    const int row0 = blockIdx.x * 64;
    const int b    = row0 >> 10;
    const int jb   = row0 & 1023;

    float wreg[64];
#pragma unroll
    for (int k = 0; k < 64; ++k) wreg[k] = Wm[k * 64 + lane];   // W[:,lane]

    const float4* gin = (const float4*)(input + (size_t)row0 * 64);
#pragma unroll
    for (int s = 0; s < 4; ++s) {
        const int id = tid + 256 * s;
        *(float4*)&ins[(id >> 4) * 68 + (id & 15) * 4] = gin[id];
    }
    if (tid < 128) wa_l[tid] = wa[tid];
    __syncthreads();

    for (int r = 0; r < 16; ++r) {
        const int row = wave * 16 + r;
        float acc = 0.f;
#pragma unroll
        for (int k4 = 0; k4 < 16; ++k4) {
            const float4 iv = *(const float4*)&ins[row * 68 + k4 * 4];   // uniform
            acc = fmaf(iv.x, wreg[k4 * 4 + 0], acc);
            acc = fmaf(iv.y, wreg[k4 * 4 + 1], acc);
            acc = fmaf(iv.z, wreg[k4 * 4 + 2], acc);
            acc = fmaf(iv.w, wreg[k4 * 4 + 3], acc);
        }
        hsT[lane * 72 + row] = (unsigned short)f32bf(acc);   // transpose in LDS
    }

    // s_src/s_dst = ins @ wa (exact fp32, independent of bf16 h)
    {
        const int r = tid & 63, kq = tid >> 6;
        float as = 0.f, ad = 0.f;
#pragma unroll
        for (int t = 0; t < 4; ++t) {
            const float4 iv = *(const float4*)&ins[r * 68 + kq * 16 + t * 4];
            const float4 ws = *(const float4*)&wa_l[kq * 16 + t * 4];
            const float4 wd = *(const float4*)&wa_l[64 + kq * 16 + t * 4];
            as = fmaf(iv.x, ws.x, fmaf(iv.y, ws.y, fmaf(iv.z, ws.z, fmaf(iv.w, ws.w, as))));
            ad = fmaf(iv.x, wd.x, fmaf(iv.y, wd.y, fmaf(iv.z, wd.z, fmaf(iv.w, wd.w, ad))));
        }
        red_s[tid] = as;
        red_d[tid] = ad;
    }
    __syncthreads();

    if (tid < 64) {
        ssrc[row0 + tid] = red_s[tid] + red_s[tid + 64] + red_s[tid + 128] + red_s[tid + 192];
        sdst[row0 + tid] = red_d[tid] + red_d[tid + 64] + red_d[tid + 128] + red_d[tid + 192];
    }

    {
        const int c = tid >> 2, part = tid & 3;
        const short8 v0 = *(const short8*)&hsT[c * 72 + part * 16];
        const short8 v1 = *(const short8*)&hsT[c * 72 + part * 16 + 8];
        const size_t g = ((size_t)(b * 64 + c)) * 1024 + jb + part * 16;
        *(short8*)&hT[g] = v0;
        *(short8*)&hT[g + 8] = v1;
    }
}

// ---------------- Kernel B: fused softmax(no-shift) + MFMA PV + ELU --------
// TI=32 rows/block. B-frags straight from L2 (hT[c][j] IS the B layout).
// p tile double-buffered in LDS -> ONE barrier per j-tile.
__global__ __launch_bounds__(256) void gat_attn(const unsigned short* __restrict__ hTg,
                                                const float* __restrict__ ssrc,
                                                const float* __restrict__ sdst,
                                                const unsigned char* __restrict__ maskB,
                                                float* __restrict__ out)
{
    __shared__ __align__(16) unsigned short p_u[2][32 * 64];  // 2 x 4 KB, swizzled
    __shared__ float psum_s[32];

    const int tid  = threadIdx.x;
    const int lane = tid & 63;
    const int wave = tid >> 6;
    const int b    = blockIdx.x & 31;
    const int i0   = (blockIdx.x >> 5) * 32;

    // p-compute role: row ii, j-octet jo
    const int ii = tid >> 3;
    const int jo = tid & 7;
    const float ssq = ssrc[b * N + i0 + ii];
    const float* __restrict__ sd = sdst + b * N;
    const unsigned char* __restrict__ mrow = maskB + (size_t)(i0 + ii) * 128;

    // MFMA role: wave owns c-tile `wave`; lane = (kq, n16)
    const int n16 = lane & 15;
    const int kq  = lane >> 4;
    const int cB  = wave * 16 + n16;
    const unsigned short* __restrict__ hTb = hTg + ((size_t)b * 64 + cB) * 1024;

    const int pwoff = ii * 64 + (jo ^ (ii & 7)) * 8;          // swizzled write slot
    const int sw    = (n16 & 7);
    const int ra0   = n16 * 64;                                // A row it=0
    const int ra1   = (16 + n16) * 64;                         // A row it=1
    const int ch0   = ((0 * 4 + kq) ^ sw) * 8;                 // k-half t=0
    const int ch1   = ((1 * 4 + kq) ^ sw) * 8;                 // k-half t=1

    floatx4 acc0 = {0.f, 0.f, 0.f, 0.f};
    floatx4 acc1 = {0.f, 0.f, 0.f, 0.f};
    float psacc = 0.f;

    auto compute_p = [&](int jt) -> short8 {
        const float4 s0 = *(const float4*)&sd[jt * 64 + jo * 8];
        const float4 s1 = *(const float4*)&sd[jt * 64 + jo * 8 + 4];
        const unsigned mb = mrow[jt * 8 + jo];
        const float ev[8] = {s0.x, s0.y, s0.z, s0.w, s1.x, s1.y, s1.z, s1.w};
        short8 r;
        float loc = 0.f;
#pragma unroll
        for (int k = 0; k < 8; ++k) {
            float t = ssq + ev[k];
            t = t > 0.f ? t : ALPHA * t;
            const float p = ((mb >> k) & 1u) ? __expf(t) : 0.f;
            loc += p;
            r[k] = (short)f32bf(p);
        }
        psacc += loc;
        return r;
    };
    auto load_B = [&](int jt, int t) -> short8 {
        return *(const short8*)&hTb[jt * 64 + t * 32 + kq * 8];
    };

    // prologue
    short8 pk = compute_p(0);
    short8 b0 = load_B(0, 0);
    short8 b1 = load_B(0, 1);

    for (int jt = 0; jt < 16; ++jt) {
        unsigned short* pb = p_u[jt & 1];
        *(short8*)&pb[pwoff] = pk;
        __syncthreads();

        // prefetch next tile (regs only; awaited by consumers next iter)
        short8 nb0 = b0, nb1 = b1, npk = pk;
        if (jt < 15) {
            nb0 = load_B(jt + 1, 0);
            nb1 = load_B(jt + 1, 1);
            npk = compute_p(jt + 1);
        }

        const short8 a00 = *(const short8*)&pb[ra0 + ch0];
        const short8 a01 = *(const short8*)&pb[ra0 + ch1];
        const short8 a10 = *(const short8*)&pb[ra1 + ch0];
        const short8 a11 = *(const short8*)&pb[ra1 + ch1];
        acc0 = __builtin_amdgcn_mfma_f32_16x16x32_bf16(a00, b0, acc0, 0, 0, 0);
        acc0 = __builtin_amdgcn_mfma_f32_16x16x32_bf16(a01, b1, acc0, 0, 0, 0);
        acc1 = __builtin_amdgcn_mfma_f32_16x16x32_bf16(a10, b0, acc1, 0, 0, 0);
        acc1 = __builtin_amdgcn_mfma_f32_16x16x32_bf16(a11, b1, acc1, 0, 0, 0);

        b0 = nb0; b1 = nb1; pk = npk;
    }

    // psum reduce across the 8 j-octet lanes sharing a row
#pragma unroll
    for (int off = 1; off < 8; off <<= 1) psacc += __shfl_xor(psacc, off, 64);
    if (jo == 0) psum_s[ii] = psacc;
    __syncthreads();

#pragma unroll
    for (int it = 0; it < 2; ++it) {
        const floatx4 acc = it ? acc1 : acc0;
#pragma unroll
        for (int r = 0; r < 4; ++r) {
            const int row = it * 16 + kq * 4 + r;   // C/D: col=lane&15, row=(lane>>4)*4+r
            const float hp = acc[r] / psum_s[row];
            const float o  = hp > 0.f ? hp : __expf(hp) - 1.f;
            out[((size_t)(b * N + i0 + row)) * 64 + cB] = o;
        }
    }
}

extern "C" void kernel_launch(void* const* d_in, const int* in_sizes, int n_in,
                              void* d_out, int out_size, void* d_ws, size_t ws_size,
                              hipStream_t stream) {
    const float* input = (const float*)d_in[0];
    const float* adj   = (const float*)d_in[1];
    const float* Wm    = (const float*)d_in[2];
    const float* a     = (const float*)d_in[3];
    float* out = (float*)d_out;

    char* ws = (char*)d_ws;
    unsigned short* hT = (unsigned short*)ws;                      // 4 MB
    float* ssrc = (float*)(ws + 4194304);                          // 128 KB
    float* sdst = (float*)(ws + 4194304 + 131072);                 // 128 KB
    unsigned long long* mask64 = (unsigned long long*)(ws + 4194304 + 2 * 131072);  // 128 KB
    float* wa = (float*)(ws + 4194304 + 3 * 131072);               // 512 B

    gat_mask<<<N * N / 64 / 4, 256, 0, stream>>>(adj, Wm, a, mask64, wa);
    gat_hs<<<B * N / 64, 256, 0, stream>>>(input, Wm, wa, hT, ssrc, sdst);
    gat_attn<<<(N / 32) * B, 256, 0, stream>>>(hT, ssrc, sdst, (const unsigned char*)mask64, out);
}

// Round 5
// 103.955 us; speedup vs baseline: 1.0137x; 1.0137x over previous
//
#include <hip/hip_runtime.h>
#include <math.h>

#define ALPHA 0.2f
#define LOG2E 1.4426950408889634f

constexpr int B = 32, N = 1024, C = 64;

typedef __attribute__((ext_vector_type(8))) short short8;
typedef __attribute__((ext_vector_type(4))) float floatx4;

static __device__ __forceinline__ unsigned f32bf(float f) {
    unsigned u = __float_as_uint(f);
    return (u + 0x7FFFu + ((u >> 16) & 1u)) >> 16;   // RNE; no NaNs here
}

static __device__ __forceinline__ void async_copy16(void* lds_base, const void* g) {
    __builtin_amdgcn_global_load_lds(
        (const __attribute__((address_space(1))) unsigned int*)g,
        (__attribute__((address_space(3))) unsigned int*)lds_base, 16, 0, 0);
}

// ---------------- K1: blocks<1024: h=input@W via MFMA (bf16), exact s vectors;
//                  blocks>=1024: adj -> bitmask -----------------------------
__global__ __launch_bounds__(256) void gat_pre(
    const float* __restrict__ input, const float* __restrict__ adj,
    const float* __restrict__ Wm, const float* __restrict__ a,
    unsigned short* __restrict__ hT, float* __restrict__ ssrc,
    float* __restrict__ sdst, unsigned long long* __restrict__ mask64)
{
    const int tid = threadIdx.x, lane = tid & 63, wave = tid >> 6;

    if (blockIdx.x >= 1024) {                       // ---- mask blocks ----
        const int mb = blockIdx.x - 1024;
#pragma unroll
        for (int t = 0; t < 4; ++t) {
            const int id = mb * 16 + wave * 4 + t;  // 0..16383
            const int i = id >> 4, jc = id & 15;
            const float av = adj[(size_t)i * N + jc * 64 + lane];
            const unsigned long long bal = __ballot(av > 0.5f);
            if (lane == 0) mask64[i * 16 + jc] = bal;
        }
        return;
    }

    __shared__ __align__(16) float W_l[64 * 65];    // padded stride 65
    __shared__ __align__(16) float a_l[128];
    __shared__ float wa_l[128];

    const int row0 = blockIdx.x * 32;
    const int b = row0 >> 10;
    const int jloc0 = row0 & 1023;
    const int m = lane & 15, kq = lane >> 4;

    // stage W (padded) + a
#pragma unroll
    for (int t = 0; t < 4; ++t) {
        const int t4 = tid + t * 256;
        const int base = t4 * 4;
        *(float4*)&W_l[(base >> 6) * 65 + (base & 63)] = ((const float4*)Wm)[t4];
    }
    if (tid < 32) ((float4*)a_l)[tid] = ((const float4*)a)[tid];

    // A-operand fp32 loads (rows shared by all waves; L1-hot redundancy)
    float af[2][2][8];
#pragma unroll
    for (int at = 0; at < 2; ++at)
#pragma unroll
        for (int kc = 0; kc < 2; ++kc) {
            const float* src = &input[(size_t)(row0 + at * 16 + m) * 64 + kc * 32 + kq * 8];
            const float4 v0 = *(const float4*)src;
            const float4 v1 = *(const float4*)(src + 4);
            af[at][kc][0] = v0.x; af[at][kc][1] = v0.y; af[at][kc][2] = v0.z; af[at][kc][3] = v0.w;
            af[at][kc][4] = v1.x; af[at][kc][5] = v1.y; af[at][kc][6] = v1.z; af[at][kc][7] = v1.w;
        }

    __syncthreads();                                // W_l, a_l visible

    // waves 0,1: wa = W @ a_{src,dst}  (rotated reads: 2-way banks = free)
    if (wave < 2) {
        const float* arow = a_l + wave * 64;
        float acc = 0.f;
        for (int t = 0; t < 64; ++t) {
            const int c = (t + lane) & 63;
            acc = fmaf(W_l[lane * 65 + c], arow[c], acc);
        }
        wa_l[wave * 64 + lane] = acc;
    }

    // B-frags from W_l (B[k][n], n = wave*16+m), A cvt, 4 MFMAs
    short8 bfr[2];
#pragma unroll
    for (int kc = 0; kc < 2; ++kc)
#pragma unroll
        for (int e = 0; e < 8; ++e)
            bfr[kc][e] = (short)f32bf(W_l[(kc * 32 + kq * 8 + e) * 65 + wave * 16 + m]);

    floatx4 acc[2] = {{0.f,0.f,0.f,0.f},{0.f,0.f,0.f,0.f}};
#pragma unroll
    for (int at = 0; at < 2; ++at) {
        short8 afr0, afr1;
#pragma unroll
        for (int e = 0; e < 8; ++e) {
            afr0[e] = (short)f32bf(af[at][0][e]);
            afr1[e] = (short)f32bf(af[at][1][e]);
        }
        acc[at] = __builtin_amdgcn_mfma_f32_16x16x32_bf16(afr0, bfr[0], acc[at], 0, 0, 0);
        acc[at] = __builtin_amdgcn_mfma_f32_16x16x32_bf16(afr1, bfr[1], acc[at], 0, 0, 0);
    }

    __syncthreads();                                // wa_l ready

    // exact fp32 s vectors, pre-scaled by 1/ln2 for exp2 downstream
#pragma unroll
    for (int at = 0; at < 2; ++at) {
        float vs = 0.f, vd = 0.f;
#pragma unroll
        for (int kc = 0; kc < 2; ++kc)
#pragma unroll
            for (int e = 0; e < 8; ++e) {
                const float x = af[at][kc][e];
                vs = fmaf(x, wa_l[kc * 32 + kq * 8 + e], vs);
                vd = fmaf(x, wa_l[64 + kc * 32 + kq * 8 + e], vd);
            }
        vs += __shfl_xor(vs, 16, 64); vs += __shfl_xor(vs, 32, 64);
        vd += __shfl_xor(vd, 16, 64); vd += __shfl_xor(vd, 32, 64);
        if (wave == 0 && kq == 0) ssrc[row0 + at * 16 + m] = vs * LOG2E;
        if (wave == 1 && kq == 0) sdst[row0 + at * 16 + m] = vd * LOG2E;
    }

    // hT[c][j] store: C/D row=kq*4+r (j), col=lane&15 (c offset); 4 consecutive j
#pragma unroll
    for (int at = 0; at < 2; ++at) {
        const uint2 v = {f32bf(acc[at][0]) | (f32bf(acc[at][1]) << 16),
                         f32bf(acc[at][2]) | (f32bf(acc[at][3]) << 16)};
        const size_t off = ((size_t)(b * 64 + wave * 16 + m)) * 1024 + jloc0 + at * 16 + kq * 4;
        *(uint2*)&hT[off] = v;
    }
}

// ---------------- K2: fused softmax(no-shift, exp2 domain) + MFMA PV + ELU --
// TI=32, R3-style 2-barrier tiles; h staged via global_load_lds w/ source-side
// XOR swizzle; sd in LDS; masks in 4 VGPRs.
__global__ __launch_bounds__(256) void gat_attn(
    const unsigned short* __restrict__ hTg, const float* __restrict__ ssrc,
    const float* __restrict__ sdst, const unsigned char* __restrict__ maskB,
    float* __restrict__ out)
{
    __shared__ __align__(16) unsigned short h_u[64 * 64];   // 8 KB swizzled [c][j]
    __shared__ __align__(16) unsigned short p_u[32 * 64];   // 4 KB swizzled [i][j]
    __shared__ __align__(16) float sd_l[1024];              // 4 KB
    __shared__ float psum_s[32];

    const int tid = threadIdx.x, lane = tid & 63, wave = tid >> 6;
    const int b = blockIdx.x & 31;
    const int i0 = (blockIdx.x >> 5) * 32;

    ((float4*)sd_l)[tid] = ((const float4*)(sdst + b * N))[tid];   // stage sd

    const int ii = tid >> 3, jo = tid & 7;                  // p role
    const float ssq = ssrc[b * N + i0 + ii];
    const unsigned char* __restrict__ mrow = maskB + (size_t)(i0 + ii) * 128;

    unsigned mreg[4];                                       // 16 tile-bytes
#pragma unroll
    for (int q = 0; q < 4; ++q) {
        unsigned v = 0;
#pragma unroll
        for (int t = 0; t < 4; ++t)
            v |= (unsigned)mrow[(q * 4 + t) * 8 + jo] << (t * 8);
        mreg[q] = v;
    }

    const int n16 = lane & 15, kq = lane >> 4;              // MFMA role
    const int cB = wave * 16 + n16;
    const unsigned short* __restrict__ hTb = hTg + (size_t)b * 64 * 1024;

    const int rr = lane >> 3;                               // async-stage row
    const int sg = (lane & 7) ^ rr;                         // global chunk (src-side swizzle)
    const int pwoff = ii * 64 + (jo ^ (ii & 7)) * 8;

    floatx4 acc0 = {0.f,0.f,0.f,0.f}, acc1 = {0.f,0.f,0.f,0.f};
    float psacc = 0.f;

#pragma unroll
    for (int jt = 0; jt < 16; ++jt) {
        __syncthreads();                                    // (A) prev reads done

#pragma unroll
        for (int s = 0; s < 2; ++s) {                       // async h tile: 8 KB
            const int r8 = wave * 16 + s * 8;
            async_copy16(&h_u[r8 * 64],
                         hTb + (size_t)(r8 + rr) * 1024 + jt * 64 + sg * 8);
        }

        const unsigned mb = (mreg[jt >> 2] >> ((jt & 3) * 8)) & 0xffu;
        const float4 s0 = *(const float4*)&sd_l[jt * 64 + jo * 8];
        const float4 s1 = *(const float4*)&sd_l[jt * 64 + jo * 8 + 4];
        const float ev[8] = {s0.x, s0.y, s0.z, s0.w, s1.x, s1.y, s1.z, s1.w};
        short8 pk;
        float loc = 0.f;
#pragma unroll
        for (int k = 0; k < 8; ++k) {
            float t = ssq + ev[k];                          // scores pre-scaled by 1/ln2
            t = t > 0.f ? t : ALPHA * t;                    // lrelu commutes w/ pos scale
            const float p = ((mb >> k) & 1u) ? exp2f(t) : 0.f;
            loc += p;
            pk[k] = (short)f32bf(p);
        }
        psacc += loc;
        *(short8*)&p_u[pwoff] = pk;

        __syncthreads();                                    // (B) h_u (vmcnt) + p_u ready

#pragma unroll
        for (int kc = 0; kc < 2; ++kc) {
            const int ch = ((kc * 4 + kq) ^ (cB & 7)) * 8;
            const int ca = ((kc * 4 + kq) ^ (n16 & 7)) * 8;
            const short8 bfr = *(const short8*)&h_u[cB * 64 + ch];
            const short8 a0  = *(const short8*)&p_u[n16 * 64 + ca];
            const short8 a1  = *(const short8*)&p_u[(16 + n16) * 64 + ca];
            acc0 = __builtin_amdgcn_mfma_f32_16x16x32_bf16(a0, bfr, acc0, 0, 0, 0);
            acc1 = __builtin_amdgcn_mfma_f32_16x16x32_bf16(a1, bfr, acc1, 0, 0, 0);
        }
    }

    psacc += __shfl_xor(psacc, 1, 64);
    psacc += __shfl_xor(psacc, 2, 64);
    psacc += __shfl_xor(psacc, 4, 64);
    if (jo == 0) psum_s[ii] = psacc;
    __syncthreads();

#pragma unroll
    for (int it = 0; it < 2; ++it) {
        const floatx4 acc = it ? acc1 : acc0;
#pragma unroll
        for (int r = 0; r < 4; ++r) {
            const int row = it * 16 + kq * 4 + r;           // C/D: col=lane&15, row=kq*4+r
            const float hp = acc[r] / psum_s[row];
            const float o = hp > 0.f ? hp : __expf(hp) - 1.f;
            out[((size_t)(b * N + i0 + row)) * 64 + cB] = o;
        }
    }
}

extern "C" void kernel_launch(void* const* d_in, const int* in_sizes, int n_in,
                              void* d_out, int out_size, void* d_ws, size_t ws_size,
                              hipStream_t stream) {
    const float* input = (const float*)d_in[0];
    const float* adj   = (const float*)d_in[1];
    const float* Wm    = (const float*)d_in[2];
    const float* a     = (const float*)d_in[3];
    float* out = (float*)d_out;

    char* ws = (char*)d_ws;
    unsigned short* hT = (unsigned short*)ws;                                   // 4 MB
    float* ssrc = (float*)(ws + 4194304);                                       // 128 KB
    float* sdst = (float*)(ws + 4194304 + 131072);                              // 128 KB
    unsigned long long* mask64 = (unsigned long long*)(ws + 4194304 + 2 * 131072); // 128 KB

    gat_pre<<<2048, 256, 0, stream>>>(input, adj, Wm, a, hT, ssrc, sdst, mask64);
    gat_attn<<<1024, 256, 0, stream>>>(hT, ssrc, sdst, (const unsigned char*)mask64, out);
}